// Round 2
// baseline (228.818 us; speedup 1.0000x reference)
//
#include <hip/hip_runtime.h>
#include <cstdint>
#include <cstddef>

// Problem constants (from reference)
#define B_ 16
#define S_ 24
#define L_ 128
#define D_ 768
#define A_ 8
#define T_ 8
#define NSLOT 24        // 3 arg types (predicate/arg0/arg1) * A
#define HALF_D 384      // each block handles half of D
#define THREADS 192     // 3 waves; 2 dims per thread over HALF_D
#define CHUNK 8         // rows per load batch; 4 batches in flight (rotating)

// native clang vector type so __builtin_nontemporal_load accepts it
typedef float f2 __attribute__((ext_vector_type(2)));

__global__ void __launch_bounds__(THREADS)
srl_kernel(const float* __restrict__ emb,            // fp32 [B,S,L,D]
           const int* __restrict__ masks,            // [B,S,L]
           const int* __restrict__ sids,             // [B,S,L]
           const int* __restrict__ pred,             // [B,S,A,T]
           const int* __restrict__ arg0,             // [B,S,A,T]
           const int* __restrict__ arg1,             // [B,S,A,T]
           float* __restrict__ out)                  // fp32: [B,S,D] ++ 3x[B,S,A,D]
{
    const int blk  = blockIdx.x;     // 0..767
    const int bs   = blk >> 1;       // sentence index 0..383
    const int half = blk & 1;        // which D half
    const int tid  = threadIdx.x;

    __shared__ int          sid_sh[L_];
    __shared__ float        mval_sh[L_];
    __shared__ float        inv_mask_cnt;
    __shared__ int          id_st[NSLOT][T_];
    __shared__ int          cnt_st[NSLOT][T_];
    __shared__ int          chosen_id[NSLOT];
    __shared__ float        inv_cnt[NSLOT];
    __shared__ unsigned int lmask[L_];
    __shared__ float        slot_acc[NSLOT][HALF_D];   // 36 KB

    // ---- stage sentence ids + mask values ----
    if (tid < L_) {
        sid_sh[tid]  = sids[bs * L_ + tid];
        mval_sh[tid] = (float)masks[bs * L_ + tid];
    }
    __syncthreads();

    // ---- per (slot, t) candidate: id + match count (192 pairs == 192 threads) ----
    {
        const int s24 = tid >> 3;   // 0..23
        const int t   = tid & 7;
        const int g   = s24 >> 3;   // arg type
        const int a   = s24 & 7;
        const int* argp = (g == 0) ? pred : (g == 1) ? arg0 : arg1;
        const int id = argp[((bs * A_) + a) * T_ + t];
        int cnt = 0;
        if (id != 0) {
            #pragma unroll 8
            for (int l = 0; l < L_; ++l) cnt += (sid_sh[l] == id) ? 1 : 0;
        }
        id_st[s24][t]  = id;
        cnt_st[s24][t] = cnt;
    }

    // zero slot accumulators; sync before use below
    {
        float* p = &slot_acc[0][0];
        for (int i = tid; i < NSLOT * HALF_D; i += THREADS) p[i] = 0.0f;
    }
    // wave-parallel mask count (was a serial 128-iter loop on tid==0)
    if (tid < 64) {
        float c = mval_sh[tid] + mval_sh[tid + 64];
        #pragma unroll
        for (int off = 32; off > 0; off >>= 1)
            c += __shfl_down(c, off, 64);
        if (tid == 0) inv_mask_cnt = 1.0f / fmaxf(c, 1.0f);
    }
    __syncthreads();

    // ---- choose LAST valid t per slot (reference overwrite semantics) ----
    if (tid < NSLOT) {
        int cid = -1;   // sentinel: never equals a sentence id (ids >= 0)
        int ccnt = 0;
        for (int t = T_ - 1; t >= 0; --t) {
            if (cnt_st[tid][t] > 0) { cid = id_st[tid][t]; ccnt = cnt_st[tid][t]; break; }
        }
        chosen_id[tid] = cid;
        inv_cnt[tid]   = (ccnt > 0) ? (1.0f / (float)ccnt) : 0.0f;
    }
    __syncthreads();

    // ---- per-row slot-match bitmask (block-uniform hot-loop condition) ----
    if (tid < L_) {
        const int s = sid_sh[tid];
        unsigned int m = 0;
        #pragma unroll
        for (int k = 0; k < NSLOT; ++k)
            m |= (unsigned int)(chosen_id[k] == s) << k;
        lmask[tid] = m;
    }
    __syncthreads();

    // ---- main streaming pass: 4 rotating register batches (32 loads in flight) ----
    // Depth arithmetic: each batch's ~900-cycle HBM latency hides under 3 PROCBs
    // of own-wave work (~480 cyc) x ~2.25 resident waves/SIMD ~= 1080 cyc cover.
    // Named buffers only (runtime-indexed reg arrays spill to scratch).
    // Row processing order is strictly 0..127 -> bit-exact vs reference order.
    const int d0 = half * HALF_D + 2 * tid;   // two dims per thread
    const float* rp = emb + (size_t)bs * (L_ * D_) + d0;
    float p0 = 0.0f, p1 = 0.0f;
    f2 va[CHUNK], vb[CHUNK], vc[CHUNK], vd[CHUNK];

#define LOADB(buf, base)                                                      \
    _Pragma("unroll")                                                         \
    for (int j = 0; j < CHUNK; ++j)                                           \
        buf[j] = __builtin_nontemporal_load(                                  \
            (const f2*)(rp + (size_t)((base) + j) * D_));

#define PROCB(buf, base)                                                      \
    _Pragma("unroll")                                                         \
    for (int j = 0; j < CHUNK; ++j) {                                         \
        const int l = (base) + j;                                             \
        const float mk = mval_sh[l];                                          \
        p0 = fmaf(buf[j].x, mk, p0);                                          \
        p1 = fmaf(buf[j].y, mk, p1);                                          \
        unsigned int m = lmask[l];        /* block-uniform branch */          \
        while (m) {                                                           \
            const int s24 = __ffs(m) - 1;                                     \
            m &= m - 1;                                                       \
            float* ap = &slot_acc[s24][2 * tid];   /* private dims, 2-way */  \
            ap[0] += buf[j].x;                                                \
            ap[1] += buf[j].y;                                                \
        }                                                                     \
    }

    LOADB(va, 0)
    LOADB(vb, CHUNK)
    LOADB(vc, 2 * CHUNK)
    for (int l0 = 0; l0 < L_; l0 += 4 * CHUNK) {
        LOADB(vd, l0 + 3 * CHUNK)                   // always valid (max 120)
        PROCB(va, l0)
        if (l0 + 4 * CHUNK < L_) { LOADB(va, l0 + 4 * CHUNK) }
        PROCB(vb, l0 + CHUNK)
        if (l0 + 5 * CHUNK < L_) { LOADB(vb, l0 + 5 * CHUNK) }
        PROCB(vc, l0 + 2 * CHUNK)
        if (l0 + 6 * CHUNK < L_) { LOADB(vc, l0 + 6 * CHUNK) }
        PROCB(vd, l0 + 3 * CHUNK)
    }
#undef LOADB
#undef PROCB
    // no sync needed: each thread reads back only the slot_acc dims it wrote

    // ---- epilogue (fp32 output, nontemporal float2 stores, 8B aligned) ----
    // output 0: mean-pooled sentence embeddings
    {
        f2 o;
        o.x = p0 * inv_mask_cnt;
        o.y = p1 * inv_mask_cnt;
        __builtin_nontemporal_store(o, (f2*)(out + (size_t)bs * D_ + d0));
    }
    // outputs 1..3: predicate / arg0 / arg1 embeddings
    const size_t out0_sz = (size_t)B_ * S_ * D_;
    const size_t arg_sz  = (size_t)B_ * S_ * A_ * D_;
    #pragma unroll
    for (int s24 = 0; s24 < NSLOT; ++s24) {
        const int g = s24 >> 3;
        const int a = s24 & 7;
        const float ic = inv_cnt[s24];        // 0 when no valid token -> exact zeros
        const float* ap = &slot_acc[s24][2 * tid];
        f2 o;
        o.x = ap[0] * ic;
        o.y = ap[1] * ic;
        float* dst = out + out0_sz + (size_t)g * arg_sz
                   + ((size_t)(bs * A_ + a)) * D_ + d0;
        __builtin_nontemporal_store(o, (f2*)dst);
    }
}

extern "C" void kernel_launch(void* const* d_in, const int* in_sizes, int n_in,
                              void* d_out, int out_size, void* d_ws, size_t ws_size,
                              hipStream_t stream) {
    const float* emb = (const float*)d_in[0];
    const int* masks = (const int*)d_in[1];
    const int* sids  = (const int*)d_in[2];
    const int* pred  = (const int*)d_in[3];
    const int* a0    = (const int*)d_in[4];
    const int* a1    = (const int*)d_in[5];
    float* out = (float*)d_out;

    srl_kernel<<<dim3(2 * B_ * S_), dim3(THREADS), 0, stream>>>(
        emb, masks, sids, pred, a0, a1, out);
}

// Round 3
// 219.972 us; speedup vs baseline: 1.0402x; 1.0402x over previous
//
#include <hip/hip_runtime.h>
#include <cstdint>
#include <cstddef>

// Problem constants (from reference)
#define B_ 16
#define S_ 24
#define L_ 128
#define D_ 768
#define A_ 8
#define T_ 8
#define NSLOT 24        // 3 arg types (predicate/arg0/arg1) * A
#define HALF_D 384      // each block handles half of D
#define THREADS 192     // 3 waves; 2 dims per thread over HALF_D
#define CHUNK 16        // rows per load batch; 2 batches in flight (ping-pong)

// native clang vector type so __builtin_nontemporal_load accepts it
typedef float f2 __attribute__((ext_vector_type(2)));

__global__ void __launch_bounds__(THREADS)
srl_kernel(const float* __restrict__ emb,            // fp32 [B,S,L,D]
           const int* __restrict__ masks,            // [B,S,L]
           const int* __restrict__ sids,             // [B,S,L]
           const int* __restrict__ pred,             // [B,S,A,T]
           const int* __restrict__ arg0,             // [B,S,A,T]
           const int* __restrict__ arg1,             // [B,S,A,T]
           float* __restrict__ out)                  // fp32: [B,S,D] ++ 3x[B,S,A,D]
{
    const int blk  = blockIdx.x;     // 0..767
    const int bs   = blk >> 1;       // sentence index 0..383
    const int half = blk & 1;        // which D half
    const int tid  = threadIdx.x;

    __shared__ int          sid_sh[L_];
    __shared__ float        mval_sh[L_];
    __shared__ float        inv_mask_cnt;
    __shared__ int          id_st[NSLOT][T_];
    __shared__ int          cnt_st[NSLOT][T_];
    __shared__ int          chosen_id[NSLOT];
    __shared__ float        inv_cnt[NSLOT];
    __shared__ unsigned int lmask[L_];
    __shared__ float        slot_acc[NSLOT][HALF_D];   // 36 KB

    // ---- stage sentence ids + mask values ----
    if (tid < L_) {
        sid_sh[tid]  = sids[bs * L_ + tid];
        mval_sh[tid] = (float)masks[bs * L_ + tid];
    }
    __syncthreads();

    // ---- per (slot, t) candidate: id + match count (192 pairs == 192 threads) ----
    {
        const int s24 = tid >> 3;   // 0..23
        const int t   = tid & 7;
        const int g   = s24 >> 3;   // arg type
        const int a   = s24 & 7;
        const int* argp = (g == 0) ? pred : (g == 1) ? arg0 : arg1;
        const int id = argp[((bs * A_) + a) * T_ + t];
        int cnt = 0;
        if (id != 0) {
            #pragma unroll 8
            for (int l = 0; l < L_; ++l) cnt += (sid_sh[l] == id) ? 1 : 0;
        }
        id_st[s24][t]  = id;
        cnt_st[s24][t] = cnt;
    }

    // zero slot accumulators; sync before use below
    {
        float* p = &slot_acc[0][0];
        for (int i = tid; i < NSLOT * HALF_D; i += THREADS) p[i] = 0.0f;
    }
    // wave-parallel mask count (replaces serial 128-iter loop on tid==0)
    if (tid < 64) {
        float c = mval_sh[tid] + mval_sh[tid + 64];
        #pragma unroll
        for (int off = 32; off > 0; off >>= 1)
            c += __shfl_down(c, off, 64);
        if (tid == 0) inv_mask_cnt = 1.0f / fmaxf(c, 1.0f);
    }
    __syncthreads();

    // ---- choose LAST valid t per slot (reference overwrite semantics) ----
    if (tid < NSLOT) {
        int cid = -1;   // sentinel: never equals a sentence id (ids >= 0)
        int ccnt = 0;
        for (int t = T_ - 1; t >= 0; --t) {
            if (cnt_st[tid][t] > 0) { cid = id_st[tid][t]; ccnt = cnt_st[tid][t]; break; }
        }
        chosen_id[tid] = cid;
        inv_cnt[tid]   = (ccnt > 0) ? (1.0f / (float)ccnt) : 0.0f;
    }
    __syncthreads();

    // ---- per-row slot-match bitmask (block-uniform hot-loop condition) ----
    if (tid < L_) {
        const int s = sid_sh[tid];
        unsigned int m = 0;
        #pragma unroll
        for (int k = 0; k < NSLOT; ++k)
            m |= (unsigned int)(chosen_id[k] == s) << k;
        lmask[tid] = m;
    }
    __syncthreads();

    // ---- main streaming pass: 2-buffer ping-pong, CHUNK=16 (32 loads in flight) ----
    // R1 structure (known-good) with doubled in-flight bytes: 2 x 16 x 512B
    // = 16 KB outstanding per wave. Simple sequential ping-pong (no 4-buffer
    // rotation: that variant regressed, suspected codegen/addressing cost).
    // Row processing order strictly 0..127 -> bit-exact vs reference.
    const int d0 = half * HALF_D + 2 * tid;   // two dims per thread
    const float* rp = emb + (size_t)bs * (L_ * D_) + d0;
    float p0 = 0.0f, p1 = 0.0f;
    f2 va[CHUNK], vb[CHUNK];

#define LOADB(buf, base)                                                      \
    _Pragma("unroll")                                                         \
    for (int j = 0; j < CHUNK; ++j)                                           \
        buf[j] = __builtin_nontemporal_load(                                  \
            (const f2*)(rp + (size_t)((base) + j) * D_));

#define PROCB(buf, base)                                                      \
    _Pragma("unroll")                                                         \
    for (int j = 0; j < CHUNK; ++j) {                                         \
        const int l = (base) + j;                                             \
        const float mk = mval_sh[l];                                          \
        p0 = fmaf(buf[j].x, mk, p0);                                          \
        p1 = fmaf(buf[j].y, mk, p1);                                          \
        unsigned int m = lmask[l];        /* block-uniform branch */          \
        while (m) {                                                           \
            const int s24 = __ffs(m) - 1;                                     \
            m &= m - 1;                                                       \
            float* ap = &slot_acc[s24][2 * tid];   /* private dims, 2-way */  \
            ap[0] += buf[j].x;                                                \
            ap[1] += buf[j].y;                                                \
        }                                                                     \
    }

    LOADB(va, 0)
    for (int l0 = 0; l0 < L_; l0 += 2 * CHUNK) {
        LOADB(vb, l0 + CHUNK)                       // prefetch batch k+1
        PROCB(va, l0)                               // consume batch k
        if (l0 + 2 * CHUNK < L_) {
            LOADB(va, l0 + 2 * CHUNK)               // prefetch batch k+2
        }
        PROCB(vb, l0 + CHUNK)                       // consume batch k+1
    }
#undef LOADB
#undef PROCB
    // no sync needed: each thread reads back only the slot_acc dims it wrote

    // ---- epilogue (fp32 output, float2 stores, 8B aligned) ----
    // output 0: mean-pooled sentence embeddings
    {
        f2 o;
        o.x = p0 * inv_mask_cnt;
        o.y = p1 * inv_mask_cnt;
        *(f2*)(out + (size_t)bs * D_ + d0) = o;
    }
    // outputs 1..3: predicate / arg0 / arg1 embeddings
    const size_t out0_sz = (size_t)B_ * S_ * D_;
    const size_t arg_sz  = (size_t)B_ * S_ * A_ * D_;
    #pragma unroll
    for (int s24 = 0; s24 < NSLOT; ++s24) {
        const int g = s24 >> 3;
        const int a = s24 & 7;
        const float ic = inv_cnt[s24];        // 0 when no valid token -> exact zeros
        const float* ap = &slot_acc[s24][2 * tid];
        f2 o;
        o.x = ap[0] * ic;
        o.y = ap[1] * ic;
        float* dst = out + out0_sz + (size_t)g * arg_sz
                   + ((size_t)(bs * A_ + a)) * D_ + d0;
        *(f2*)dst = o;
    }
}

extern "C" void kernel_launch(void* const* d_in, const int* in_sizes, int n_in,
                              void* d_out, int out_size, void* d_ws, size_t ws_size,
                              hipStream_t stream) {
    const float* emb = (const float*)d_in[0];
    const int* masks = (const int*)d_in[1];
    const int* sids  = (const int*)d_in[2];
    const int* pred  = (const int*)d_in[3];
    const int* a0    = (const int*)d_in[4];
    const int* a1    = (const int*)d_in[5];
    float* out = (float*)d_out;

    srl_kernel<<<dim3(2 * B_ * S_), dim3(THREADS), 0, stream>>>(
        emb, masks, sids, pred, a0, a1, out);
}